// Round 3
// baseline (772.208 us; speedup 1.0000x reference)
//
#include <hip/hip_runtime.h>
#include <math.h>

// Problem constants (from reference)
#define Bn    256
#define Tn    1024
#define In    64
#define Pn    256
#define En    128
#define NOUTn 64
#define LN_EPS 1e-5f

// softmax factorization constants (TEMP=8):
// z_j ∝ exp((j-2)*frac/4) * exp(-(j-2)^2/8)  (common exp(-frac^2/8) cancels)
#define C1f 0.3606737602222409f     // log2(e)/4
#define K1f 0.8824969025845955f     // exp(-1/8)
#define K2f 0.6065306597126334f     // exp(-4/8)

typedef float f32x2 __attribute__((ext_vector_type(2)));

__device__ __forceinline__ float tanh_fast(float x) {
    float e = __builtin_amdgcn_exp2f(x * 2.88539008177793f);   // e^(2x)
    return 1.0f - 2.0f * __builtin_amdgcn_rcpf(e + 1.0f);
}
__device__ __forceinline__ f32x2 tanh2(f32x2 x) {
    f32x2 e;
    e[0] = __builtin_amdgcn_exp2f(x[0] * 2.88539008177793f);
    e[1] = __builtin_amdgcn_exp2f(x[1] * 2.88539008177793f);
    f32x2 r;
    r[0] = __builtin_amdgcn_rcpf(e[0] + 1.0f);
    r[1] = __builtin_amdgcn_rcpf(e[1] + 1.0f);
    return 1.0f - 2.0f * r;
}

template<int CTRL, int RMASK>
__device__ __forceinline__ float dpp_add(float x) {
    return x + __int_as_float(__builtin_amdgcn_update_dpp(
        0, __float_as_int(x), CTRL, RMASK, 0xF, false));
}
__device__ __forceinline__ void wave_sum64_x3(float& x, float& y, float& z) {
#define LVL(C, R) x = dpp_add<C, R>(x); y = dpp_add<C, R>(y); z = dpp_add<C, R>(z);
    LVL(0x111, 0xF)
    LVL(0x112, 0xF)
    LVL(0x114, 0xF)
    LVL(0x118, 0xF)
    LVL(0x142, 0xA)
    LVL(0x143, 0xC)
#undef LVL
    x = __int_as_float(__builtin_amdgcn_readlane(__float_as_int(x), 63));
    y = __int_as_float(__builtin_amdgcn_readlane(__float_as_int(y), 63));
    z = __int_as_float(__builtin_amdgcn_readlane(__float_as_int(z), 63));
}

// ===========================================================================
// R11: FUSED (zero workspace — R10 showed ws bytes are re-poisoned per rep,
// costing ~270us for 128MB) with a chain-shortened consumer.
//
// R10 proved the consumer's serial chain is the wall (~925 cy/step) and that
// producers are fully hidden. The longest chain arm was the LDS round-trip:
//   su -> m_v -> 5x ds_write -> (in-order DS pipe) -> 6x ds_read (next-step
//   jump gather) -> lgkm wait -> ctxJ -> su'
// R11 removes it bit-exactly:
//   * The jump-gather for step t+1 is issued at the TOP of step t (addresses
//     known right after the gate), BEFORE this step's scatter. The stale
//     reads are PATCHED in registers: gather row j collides with scatter
//     row s iff s = (j + (jbase-base)) & 255 <= 4, and the fresh value is
//     m_sv (already in registers). Values are bit-identical to a
//     post-scatter LDS read.
//   * Both ctx candidates are computed in the PREVIOUS step's tail, so the
//     inter-step chain is: jl -> cndmask(E)  ||  hid -> add -> tanh -> reduce.
//     No LDS on the chain at all.
// Producers and staging identical to R9 (triple-buffered 16-step chunks).
// LDS: ring 128 KB + jd 1 KB + stage 3x8 KB = 153 KB (fits 160 KB).
// ===========================================================================
#define STAGE_FLOATS (3 * 16 * En)                 // 6144
#define LDSF_FLOATS  (Pn * En + Pn + STAGE_FLOATS) // 39168
#define LDSF_BYTES   (LDSF_FLOATS * 4)             // 156672

__global__ __launch_bounds__(192, 1)
void fused2_kernel(const float* __restrict__ x,
                   const float* __restrict__ pointer_init,
                   const float* __restrict__ W_in, const float* __restrict__ b_in,
                   const float* __restrict__ ln_w, const float* __restrict__ ln_b,
                   const float* __restrict__ jump_dest,
                   const float* __restrict__ Wg,  const float* __restrict__ bg,
                   const float* __restrict__ cs_ptr,
                   const float* __restrict__ Wo,  const float* __restrict__ bo,
                   float* __restrict__ out) {
    extern __shared__ float lds[];
    float* mem = lds;                    // ring: [row][2*l + c]
    float* jd  = lds + Pn * En;          // jump_dest copy
    float* stg = lds + Pn * En + Pn;     // stage: [buf3][tq4][e128][t4]

    const int b   = blockIdx.x;
    const int tid = threadIdx.x;

    if (tid >= 64) {
        // ================= PRODUCERS (waves 1,2): 4t x 4e register tile ======
        const int p    = tid - 64;        // 0..127
        const int tq   = p >> 5;          // 0..3 : which 4-t group of the chunk
        const int eidx = p & 31;          // e = eidx + 32*j, j=0..3
        float be[4];
        #pragma unroll
        for (int j = 0; j < 4; ++j) be[j] = b_in[eidx + 32 * j];
        const float* xb = x + (size_t)b * Tn * In;

#define PRODUCE(K, BUF) {                                                     \
    const int t0 = (K) * 16 + tq * 4;                                         \
    const float4* xr = (const float4*)(xb + t0 * In);   /* per-lane addr */   \
    float acc[4][4];                                                          \
    _Pragma("unroll")                                                         \
    for (int tt = 0; tt < 4; ++tt)                                            \
        _Pragma("unroll")                                                     \
        for (int j = 0; j < 4; ++j) acc[tt][j] = 0.f;                         \
    _Pragma("unroll")                                                         \
    for (int i4 = 0; i4 < 16; ++i4) {                                         \
        float4 xv[4];                                                         \
        _Pragma("unroll")                                                     \
        for (int tt = 0; tt < 4; ++tt) xv[tt] = xr[tt * 16 + i4];             \
        float4 wf[4];                                                         \
        _Pragma("unroll")                                                     \
        for (int j = 0; j < 4; ++j)                                           \
            wf[j] = *(const float4*)(W_in + (eidx + 32 * j) * In + i4 * 4);   \
        _Pragma("unroll")                                                     \
        for (int tt = 0; tt < 4; ++tt)                                        \
            _Pragma("unroll")                                                 \
            for (int j = 0; j < 4; ++j) {                                     \
                acc[tt][j] += xv[tt].x * wf[j].x;                             \
                acc[tt][j] += xv[tt].y * wf[j].y;                             \
                acc[tt][j] += xv[tt].z * wf[j].z;                             \
                acc[tt][j] += xv[tt].w * wf[j].w;                             \
            }                                                                 \
    }                                                                         \
    float* sg = stg + (BUF) * 2048 + tq * 512;                                \
    _Pragma("unroll")                                                         \
    for (int j = 0; j < 4; ++j) {                                             \
        float4 o;                                                             \
        o.x = tanh_fast(acc[0][j] + be[j]);                                   \
        o.y = tanh_fast(acc[1][j] + be[j]);                                   \
        o.z = tanh_fast(acc[2][j] + be[j]);                                   \
        o.w = tanh_fast(acc[3][j] + be[j]);                                   \
        *(float4*)(sg + (eidx + 32 * j) * 4) = o;                             \
    }                                                                         \
}
        PRODUCE(0, 0)
        PRODUCE(1, 1)
        __syncthreads();                   // #1: chunks 0,1 staged
        int buf = 2;
        for (int k = 0; k < 64; ++k) {
            if (k + 2 < 64) {
                PRODUCE(k + 2, buf)
                buf = (buf == 2) ? 0 : buf + 1;
            }
            __syncthreads();               // chunk boundary
        }
#undef PRODUCE
        __syncthreads();                   // final: hid broadcast
        return;
    }

    // ================= CONSUMER (wave 0) =====================================
    const int l = tid;

    float4* m4 = (float4*)mem;
    for (int i = l; i < Pn * En / 4; i += 64) m4[i] = make_float4(0.f, 0.f, 0.f, 0.f);
    for (int i = l; i < Pn; i += 64) jd[i] = jump_dest[i];

    const f32x2 lnw = {ln_w[l], ln_w[l + 64]};
    const f32x2 lnb = {ln_b[l], ln_b[l + 64]};
    const f32x2 wg  = {Wg[l],   Wg[l + 64]};
    const float bgs = bg[0];
    const float cs  = 1.0f / (1.0f + expf(-cs_ptr[0]));
    f32x2 hid = {0.f, 0.f};

    float* myb = mem + 2 * l;

    // ---- pipeline state ----
    float jl = 1.0f;                       // forces JUMP at t=0
    float z0 = 0.f, z1 = 0.f, z2 = 1.f, z3 = 0.f, z4 = 0.f, inv = 1.f;
    float ptrW = 0.f; int baseW = 0; float jtW_pre = 0.f;
    f32x2 wnb0 = {0,0}, wnb1 = {0,0}, wnb2 = {0,0}, wnb3 = {0,0}, wnb4 = {0,0};
    float *wp0 = myb, *wp1 = myb, *wp2 = myb, *wp3 = myb, *wp4 = myb;
    // JUMP candidate: from pointer_init
    float jptr  = pointer_init[b];
    int   jbase = (int)jptr; jbase = jbase > 255 ? 255 : jbase;
    float jz0, jz1, jz2 = 1.f, jz3, jz4, jinv;
    {
        const float frac = jptr - (float)jbase;
        const float r  = __builtin_amdgcn_exp2f(frac * C1f);
        const float ri = __builtin_amdgcn_exp2f(-frac * C1f);
        jz0 = K2f * ri * ri; jz1 = K1f * ri;
        jz3 = K1f * r;       jz4 = K2f * r * r;
        jinv = __builtin_amdgcn_rcpf(((jz0 + jz1) + (jz2 + jz3)) + jz4);
    }
    float *jp0 = mem + (((jbase + 254) & 255) << 7) + 2 * l;
    float *jp1 = mem + (((jbase + 255) & 255) << 7) + 2 * l;
    float *jp2 = mem + ((jbase) << 7) + 2 * l;
    float *jp3 = mem + (((jbase + 1) & 255) << 7) + 2 * l;
    float *jp4 = mem + (((jbase + 2) & 255) << 7) + 2 * l;
    f32x2 jnb0, jnb1, jnb2, jnb3, jnb4;
    float jjt;
    f32x2 ctxW, ctxJ;

    __syncthreads();                       // #1: mem zeroed, jd filled, stage 0,1

    jnb0 = *(f32x2*)jp0; jnb1 = *(f32x2*)jp1; jnb2 = *(f32x2*)jp2;
    jnb3 = *(f32x2*)jp3; jnb4 = *(f32x2*)jp4;
    jjt  = jd[jbase];
    // prologue ctx candidates (same inputs the old step-0 would have used)
    ctxW = inv  * (((wnb0 * z0  + wnb1 * z1 ) + (wnb2 * z2  + wnb3 * z3 ))
                   + wnb4 * z4 );
    ctxJ = jinv * (((jnb0 * jz0 + jnb1 * jz1) + (jnb2 * jz2 + jnb3 * jz3))
                   + jnb4 * jz4);

    // A = current 4-step group registers (group tb=0)
    const float* sa0 = stg + 4 * l;        // buf0, group 0, ch l
    float4 A0 = *(const float4*)sa0;
    float4 A1 = *(const float4*)(sa0 + 256);

#define SSTEP(EC0, EC1) {                                                      \
    /* E candidates: (em + cs*ctx) grouping identical to the reference path */ \
    f32x2 em; em[0] = (EC0); em[1] = (EC1);                                    \
    const f32x2 EW = em + cs * ctxW;                                           \
    const f32x2 EJ = em + cs * ctxJ;                                           \
    const bool JMP = jl > 0.0f;                 /* wave-uniform gate */        \
    f32x2 E; E[0] = JMP ? EJ[0] : EW[0]; E[1] = JMP ? EJ[1] : EW[1];           \
    /* commit selected state (off the su path) */                              \
    const float ptr  = JMP ? jptr  : ptrW;                                     \
    const int   base = JMP ? jbase : baseW;                                    \
    z0 = JMP ? jz0 : z0;  z1 = JMP ? jz1 : z1;                                 \
    z3 = JMP ? jz3 : z3;  z4 = JMP ? jz4 : z4;                                 \
    inv = JMP ? jinv : inv;                                                    \
    const f32x2 nb0 = JMP ? jnb0 : wnb0;                                       \
    const f32x2 nb1 = JMP ? jnb1 : wnb1;                                       \
    const f32x2 nb2 = JMP ? jnb2 : wnb2;                                       \
    const f32x2 nb3 = JMP ? jnb3 : wnb3;                                       \
    const f32x2 nb4 = JMP ? jnb4 : wnb4;                                       \
    float* p0 = JMP ? jp0 : wp0;  float* p1 = JMP ? jp1 : wp1;                 \
    float* p2 = JMP ? jp2 : wp2;  float* p3 = JMP ? jp3 : wp3;                 \
    float* p4 = JMP ? jp4 : wp4;                                               \
    const float jt_n = JMP ? jjt : jtW_pre;                                    \
    /* next-step jump prep; EARLY LDS reads (issued BEFORE this step's        \
       scatter; stale overlaps patched below, bit-exactly) */                  \
    jptr  = jt_n;                                                              \
    jbase = (int)jptr; jbase = jbase > 255 ? 255 : jbase;                      \
    const int dov = (jbase - base) & 255;                                      \
    jp0 = mem + (((jbase + 254) & 255) << 7) + 2 * l;                          \
    jp1 = mem + (((jbase + 255) & 255) << 7) + 2 * l;                          \
    jp2 = mem + ((jbase) << 7) + 2 * l;                                        \
    jp3 = mem + (((jbase + 1) & 255) << 7) + 2 * l;                            \
    jp4 = mem + (((jbase + 2) & 255) << 7) + 2 * l;                            \
    const f32x2 jr0 = *(f32x2*)jp0, jr1 = *(f32x2*)jp1, jr2 = *(f32x2*)jp2,    \
                jr3 = *(f32x2*)jp3, jr4 = *(f32x2*)jp4;                        \
    float* wp4n = mem + (((base + 3) & 255) << 7) + 2 * l;                     \
    const f32x2 wnb4n = *(f32x2*)wp4n;      /* row base+3: never scattered */  \
    const int   baseWn = (base + 1) & 255;                                     \
    const float jtWn = jd[baseWn];                                             \
    const float jjtn = jd[jbase];                                              \
    {                                                                          \
        const float frac = jptr - (float)jbase;                                \
        const float r  = __builtin_amdgcn_exp2f(frac * C1f);                   \
        const float ri = __builtin_amdgcn_exp2f(-frac * C1f);                  \
        jz0 = K2f * ri * ri; jz1 = K1f * ri;                                   \
        jz3 = K1f * r;       jz4 = K2f * r * r;                                \
        jinv = __builtin_amdgcn_rcpf(((jz0 + jz1) + (jz2 + jz3)) + jz4);       \
    }                                                                          \
    /* su (the critical chain) + memory update (identical math) */             \
    const f32x2 su = tanh2(E + hid);                                           \
    const f32x2 g  = su * inv;                                                 \
    const f32x2 m0v = nb0 + z0 * g, m1v = nb1 + z1 * g, m2v = nb2 + z2 * g,    \
                m3v = nb3 + z3 * g, m4v = nb4 + z4 * g;                        \
    *(f32x2*)p0 = m0v; *(f32x2*)p1 = m1v; *(f32x2*)p2 = m2v;                   \
    *(f32x2*)p3 = m3v; *(f32x2*)p4 = m4v;                                      \
    /* walk candidate for next step */                                         \
    baseW = baseWn;                                                            \
    ptrW  = ptr + 1.0f; if (ptrW >= 256.0f) ptrW -= 256.0f;                    \
    wnb0 = m1v; wnb1 = m2v; wnb2 = m3v; wnb3 = m4v; wnb4 = wnb4n;              \
    wp0 = p1; wp1 = p2; wp2 = p3; wp3 = p4; wp4 = wp4n;                        \
    jtW_pre = jtWn;                                                            \
    jjt = jjtn;                                                                \
    /* patch: gather row j == scatter row s iff s=(j+dov)&255 <= 4; fresh     \
       value is m_sv (bit-identical to a post-scatter read) */                 \
    const int si0 = dov, si1 = (1 + dov) & 255, si2 = (2 + dov) & 255,         \
              si3 = (3 + dov) & 255, si4 = (4 + dov) & 255;                    \
    jnb0 = si0==0?m0v: si0==1?m1v: si0==2?m2v: si0==3?m3v: si0==4?m4v: jr0;    \
    jnb1 = si1==0?m0v: si1==1?m1v: si1==2?m2v: si1==3?m3v: si1==4?m4v: jr1;    \
    jnb2 = si2==0?m0v: si2==1?m1v: si2==2?m2v: si2==3?m3v: si2==4?m4v: jr2;    \
    jnb3 = si3==0?m0v: si3==1?m1v: si3==2?m2v: si3==3?m3v: si3==4?m4v: jr3;    \
    jnb4 = si4==0?m0v: si4==1?m1v: si4==2?m2v: si4==3?m3v: si4==4?m4v: jr4;    \
    /* next-step ctx candidates (same inputs as old step-start compute) */     \
    ctxW = inv  * (((wnb0 * z0  + wnb1 * z1 ) + (wnb2 * z2  + wnb3 * z3 ))     \
                   + wnb4 * z4 );                                              \
    ctxJ = jinv * (((jnb0 * jz0 + jnb1 * jz1) + (jnb2 * jz2 + jnb3 * jz3))     \
                   + jnb4 * jz4);                                              \
    /* reductions + LN + gate (identical) */                                   \
    float s1 = su[0] + su[1];                                                  \
    const f32x2 sq = su * su;  float s2 = sq[0] + sq[1];                       \
    const f32x2 sg = su * wg;  float s3v = sg[0] + sg[1];                      \
    wave_sum64_x3(s1, s2, s3v);                                                \
    const float mu   = s1 * (1.0f / En);                                       \
    const float var  = s2 * (1.0f / En) - mu * mu;                             \
    const float rstd = __builtin_amdgcn_rsqf(var + LN_EPS);                    \
    hid = (su - mu) * rstd * lnw + lnb;                                        \
    jl  = s3v + bgs;                                                           \
}

    for (int k = 0; k < 64; ++k) {
        #pragma unroll 1
        for (int gi = 0; gi < 4; ++gi) {
            const int tb  = k * 4 + gi;
            int tbn = tb + 1; if (tbn > 255) tbn = 255;
            // prefetch next group: buf[(tbn>>2)%3] is never producer-active
            const float* sb = stg + ((tbn >> 2) % 3) * 2048 + (tbn & 3) * 512 + 4 * l;
            float4 B0 = *(const float4*)sb;
            float4 B1 = *(const float4*)(sb + 256);
            SSTEP(A0.x, A1.x)
            SSTEP(A0.y, A1.y)
            SSTEP(A0.z, A1.z)
            SSTEP(A0.w, A1.w)
            A0 = B0; A1 = B1;
        }
        __syncthreads();               // chunk boundary (chunk k+2 staged)
    }
#undef SSTEP

    // epilogue: logits = hid @ Wo^T + bo
    mem[l] = hid[0]; mem[64 + l] = hid[1];
    __syncthreads();                   // final
    const float4* w4 = (const float4*)(Wo + l * En);
    const float4* h4 = (const float4*)mem;
    float a0 = 0.f, a1 = 0.f, a2 = 0.f, a3 = 0.f;
    #pragma unroll
    for (int i = 0; i < En / 4; ++i) {
        float4 wv = w4[i]; float4 hv = h4[i];
        a0 += wv.x * hv.x; a1 += wv.y * hv.y; a2 += wv.z * hv.z; a3 += wv.w * hv.w;
    }
    out[b * NOUTn + l] = (a0 + a1) + (a2 + a3) + bo[l];
}

extern "C" void kernel_launch(void* const* d_in, const int* in_sizes, int n_in,
                              void* d_out, int out_size, void* d_ws, size_t ws_size,
                              hipStream_t stream) {
    const float* x            = (const float*)d_in[0];
    const float* pointer_init = (const float*)d_in[1];
    const float* W_in         = (const float*)d_in[2];
    const float* b_in         = (const float*)d_in[3];
    const float* ln_w         = (const float*)d_in[4];
    const float* ln_b         = (const float*)d_in[5];
    const float* jump_dest    = (const float*)d_in[6];
    const float* Wg           = (const float*)d_in[7];
    const float* bg           = (const float*)d_in[8];
    const float* cs           = (const float*)d_in[9];
    const float* Wo           = (const float*)d_in[10];
    const float* bo           = (const float*)d_in[11];
    float* out = (float*)d_out;
    (void)d_ws; (void)ws_size;   // zero workspace: ws bytes are re-poisoned
                                 // per rep and billed (~270us for 128MB, R10)

    (void)hipFuncSetAttribute((const void*)fused2_kernel,
                              hipFuncAttributeMaxDynamicSharedMemorySize, LDSF_BYTES);
    fused2_kernel<<<Bn, 192, LDSF_BYTES, stream>>>(
        x, pointer_init, W_in, b_in, ln_w, ln_b, jump_dest, Wg, bg, cs,
        Wo, bo, out);
}

// Round 4
// 468.507 us; speedup vs baseline: 1.6482x; 1.6482x over previous
//
#include <hip/hip_runtime.h>
#include <math.h>

// Problem constants (from reference)
#define Bn    256
#define Tn    1024
#define In    64
#define Pn    256
#define En    128
#define NOUTn 64
#define LN_EPS 1e-5f

// softmax factorization constants (TEMP=8):
// z_j ∝ exp((j-2)*frac/4) * exp(-(j-2)^2/8)  (common exp(-frac^2/8) cancels)
#define C1f 0.3606737602222409f     // log2(e)/4
#define K1f 0.8824969025845955f     // exp(-1/8)
#define K2f 0.6065306597126334f     // exp(-4/8)

typedef float f32x2 __attribute__((ext_vector_type(2)));

__device__ __forceinline__ float tanh_fast(float x) {
    float e = __builtin_amdgcn_exp2f(x * 2.88539008177793f);   // e^(2x)
    return 1.0f - 2.0f * __builtin_amdgcn_rcpf(e + 1.0f);
}
__device__ __forceinline__ f32x2 tanh2(f32x2 x) {
    f32x2 e;
    e[0] = __builtin_amdgcn_exp2f(x[0] * 2.88539008177793f);
    e[1] = __builtin_amdgcn_exp2f(x[1] * 2.88539008177793f);
    f32x2 r;
    r[0] = __builtin_amdgcn_rcpf(e[0] + 1.0f);
    r[1] = __builtin_amdgcn_rcpf(e[1] + 1.0f);
    return 1.0f - 2.0f * r;
}

template<int CTRL, int RMASK>
__device__ __forceinline__ float dpp_add(float x) {
    return x + __int_as_float(__builtin_amdgcn_update_dpp(
        0, __float_as_int(x), CTRL, RMASK, 0xF, false));
}
__device__ __forceinline__ void wave_sum64_x3(float& x, float& y, float& z) {
#define LVL(C, R) x = dpp_add<C, R>(x); y = dpp_add<C, R>(y); z = dpp_add<C, R>(z);
    LVL(0x111, 0xF)
    LVL(0x112, 0xF)
    LVL(0x114, 0xF)
    LVL(0x118, 0xF)
    LVL(0x142, 0xA)
    LVL(0x143, 0xC)
#undef LVL
    x = __int_as_float(__builtin_amdgcn_readlane(__float_as_int(x), 63));
    y = __int_as_float(__builtin_amdgcn_readlane(__float_as_int(y), 63));
    z = __int_as_float(__builtin_amdgcn_readlane(__float_as_int(z), 63));
}

// ===========================================================================
// R12 = R8 (best measured: 394us kernel) + three bit-exact latency edits:
//   1. DPP reduce hoisted to right after su: tree latency overlaps the
//      scatter + walk-prep issue instead of following it.
//   2. Walk-path ctx precomputed in the PREVIOUS step's tail (ctxWp) from
//      the carried window (m1v..m4v, wnb4) and carried z's -- exactly the
//      operands/association the walk path would use => identical bits.
//      Walk steps' post-gate chain is now just E-add -> tanh.
//   3. s_setprio(1) on the consumer wave.
// Everything else (producers, staging, jump path, epilogue) is byte-for-byte
// the R8 structure. R9/R11's dual-candidate speculation is abandoned: it
// makes every step pay the jump cost that R8's uniform branch skips.
// LDS: ring 128 KB + jd 1 KB + stage 3x8 KB = 153 KB (fits 160 KB).
// ===========================================================================
#define STAGE_FLOATS (3 * 16 * En)                 // 6144
#define LDSF_FLOATS  (Pn * En + Pn + STAGE_FLOATS) // 39168
#define LDSF_BYTES   (LDSF_FLOATS * 4)             // 156672

__global__ __launch_bounds__(192, 1)
void fused2_kernel(const float* __restrict__ x,
                   const float* __restrict__ pointer_init,
                   const float* __restrict__ W_in, const float* __restrict__ b_in,
                   const float* __restrict__ ln_w, const float* __restrict__ ln_b,
                   const float* __restrict__ jump_dest,
                   const float* __restrict__ Wg,  const float* __restrict__ bg,
                   const float* __restrict__ cs_ptr,
                   const float* __restrict__ Wo,  const float* __restrict__ bo,
                   float* __restrict__ out) {
    extern __shared__ float lds[];
    float* mem = lds;                    // ring: [row][2*l + c]
    float* jd  = lds + Pn * En;          // jump_dest copy
    float* stg = lds + Pn * En + Pn;     // stage: [buf3][tq4][e128][t4]

    const int b   = blockIdx.x;
    const int tid = threadIdx.x;

    if (tid >= 64) {
        // ================= PRODUCERS (waves 1,2): 4t x 4e register tile ======
        const int p    = tid - 64;        // 0..127
        const int tq   = p >> 5;          // 0..3 : which 4-t group of the chunk
        const int eidx = p & 31;          // e = eidx + 32*j, j=0..3
        float be[4];
        #pragma unroll
        for (int j = 0; j < 4; ++j) be[j] = b_in[eidx + 32 * j];
        const float* xb = x + (size_t)b * Tn * In;

#define PRODUCE(K, BUF) {                                                     \
    const int t0 = (K) * 16 + tq * 4;                                         \
    const float4* xr = (const float4*)(xb + t0 * In);   /* per-lane addr */   \
    float acc[4][4];                                                          \
    _Pragma("unroll")                                                         \
    for (int tt = 0; tt < 4; ++tt)                                            \
        _Pragma("unroll")                                                     \
        for (int j = 0; j < 4; ++j) acc[tt][j] = 0.f;                         \
    _Pragma("unroll")                                                         \
    for (int i4 = 0; i4 < 16; ++i4) {                                         \
        float4 xv[4];                                                         \
        _Pragma("unroll")                                                     \
        for (int tt = 0; tt < 4; ++tt) xv[tt] = xr[tt * 16 + i4];             \
        float4 wf[4];                                                         \
        _Pragma("unroll")                                                     \
        for (int j = 0; j < 4; ++j)                                           \
            wf[j] = *(const float4*)(W_in + (eidx + 32 * j) * In + i4 * 4);   \
        _Pragma("unroll")                                                     \
        for (int tt = 0; tt < 4; ++tt)                                        \
            _Pragma("unroll")                                                 \
            for (int j = 0; j < 4; ++j) {                                     \
                acc[tt][j] += xv[tt].x * wf[j].x;                             \
                acc[tt][j] += xv[tt].y * wf[j].y;                             \
                acc[tt][j] += xv[tt].z * wf[j].z;                             \
                acc[tt][j] += xv[tt].w * wf[j].w;                             \
            }                                                                 \
    }                                                                         \
    float* sg = stg + (BUF) * 2048 + tq * 512;                                \
    _Pragma("unroll")                                                         \
    for (int j = 0; j < 4; ++j) {                                             \
        float4 o;                                                             \
        o.x = tanh_fast(acc[0][j] + be[j]);                                   \
        o.y = tanh_fast(acc[1][j] + be[j]);                                   \
        o.z = tanh_fast(acc[2][j] + be[j]);                                   \
        o.w = tanh_fast(acc[3][j] + be[j]);                                   \
        *(float4*)(sg + (eidx + 32 * j) * 4) = o;                             \
    }                                                                         \
}
        PRODUCE(0, 0)
        PRODUCE(1, 1)
        __syncthreads();                   // #1: chunks 0,1 staged
        int buf = 2;
        for (int k = 0; k < 64; ++k) {
            if (k + 2 < 64) {
                PRODUCE(k + 2, buf)
                buf = (buf == 2) ? 0 : buf + 1;
            }
            __syncthreads();               // chunk boundary
        }
#undef PRODUCE
        __syncthreads();                   // final: hid broadcast
        return;
    }

    // ================= CONSUMER (wave 0): scan, LDS-staged emb ==============
    const int l = tid;

    float4* m4 = (float4*)mem;
    for (int i = l; i < Pn * En / 4; i += 64) m4[i] = make_float4(0.f, 0.f, 0.f, 0.f);
    for (int i = l; i < Pn; i += 64) jd[i] = jump_dest[i];

    const f32x2 lnw = {ln_w[l], ln_w[l + 64]};
    const f32x2 lnb = {ln_b[l], ln_b[l + 64]};
    const f32x2 wg  = {Wg[l],   Wg[l + 64]};
    const float bgs = bg[0];
    const float cs  = 1.0f / (1.0f + expf(-cs_ptr[0]));
    f32x2 hid = {0.f, 0.f};

    float* myb = mem + 2 * l;

    // ---- pipeline state (forced jump to pointer_init at t=0) ----
    float jl      = 1.0f;
    float jt_cur  = pointer_init[b];
    float ptrW    = 0.f;
    int   baseW   = 0;
    float jtW_pre = 0.f;
    float z0 = 0.f, z1 = 0.f, z2 = 1.f, z3 = 0.f, z4 = 0.f, inv = 1.f;
    f32x2 wnb0 = {0,0}, wnb1 = {0,0}, wnb2 = {0,0}, wnb3 = {0,0}, wnb4 = {0,0};
    float *wp0 = myb, *wp1 = myb, *wp2 = myb, *wp3 = myb, *wp4 = myb;
    f32x2 ctxWp = {0.f, 0.f};              // walk-path ctx, precomputed at tail

    __syncthreads();                       // #1: emb chunks 0,1 staged
    __builtin_amdgcn_s_setprio(1);         // favor the serial wave

    // A = current 4-step group registers (group tb=0)
    const float* sa0 = stg + 4 * l;        // buf0, group 0, ch l
    float4 A0 = *(const float4*)sa0;
    float4 A1 = *(const float4*)(sa0 + 256);

#define SSTEP(EC0, EC1) {                                                      \
    float ptr; int base;                                                       \
    f32x2 nb0, nb1, nb2, nb3, nb4;                                             \
    float *p0, *p1, *p2, *p3, *p4;                                             \
    float jt_nxt;                                                              \
    f32x2 ctx;                                                                 \
    if (__builtin_amdgcn_readfirstlane(__float_as_int(jl)) > 0) {              \
        /* JUMP: full gather (issued first) + weight recompute */              \
        ptr  = jt_cur;                                                         \
        base = (int)ptr; base = base > 255 ? 255 : base;                       \
        p0 = mem + (((base + 254) & 255) << 7) + 2 * l;                        \
        p1 = mem + (((base + 255) & 255) << 7) + 2 * l;                        \
        p2 = mem + (base << 7) + 2 * l;                                        \
        p3 = mem + (((base + 1) & 255) << 7) + 2 * l;                          \
        p4 = mem + (((base + 2) & 255) << 7) + 2 * l;                          \
        nb0 = *(f32x2*)p0; nb1 = *(f32x2*)p1; nb2 = *(f32x2*)p2;               \
        nb3 = *(f32x2*)p3; nb4 = *(f32x2*)p4;                                  \
        jt_nxt = jd[base];                                                     \
        const float frac = ptr - (float)base;                                  \
        const float r  = __builtin_amdgcn_exp2f(frac * C1f);                   \
        const float ri = __builtin_amdgcn_exp2f(-frac * C1f);                  \
        z0 = K2f * ri * ri; z1 = K1f * ri; z2 = 1.0f;                          \
        z3 = K1f * r;       z4 = K2f * r * r;                                  \
        inv = __builtin_amdgcn_rcpf(((z0 + z1) + (z2 + z3)) + z4);             \
        ctx = inv * (((nb0 * z0 + nb1 * z1) + (nb2 * z2 + nb3 * z3))           \
                     + nb4 * z4);                                              \
    } else {                                                                   \
        /* WALK: weights carried; ctx PRECOMPUTED last step (same bits) */     \
        ptr = ptrW; base = baseW;                                              \
        nb0 = wnb0; nb1 = wnb1; nb2 = wnb2; nb3 = wnb3; nb4 = wnb4;            \
        p0 = wp0; p1 = wp1; p2 = wp2; p3 = wp3; p4 = wp4;                      \
        jt_nxt = jtW_pre;                                                      \
        ctx = ctxWp;                                                           \
    }                                                                          \
    f32x2 em; em[0] = (EC0); em[1] = (EC1);                                    \
    const f32x2 su = tanh2(em + cs * ctx + hid);                               \
    /* HOISTED reduce: tree issues immediately; scatter/prep run under it */   \
    float s1 = su[0] + su[1];                                                  \
    const f32x2 sq = su * su;  float s2 = sq[0] + sq[1];                       \
    const f32x2 sg = su * wg;  float s3 = sg[0] + sg[1];                       \
    wave_sum64_x3(s1, s2, s3);                                                 \
    /* scatter + next-walk prep (independent of tree) */                       \
    const f32x2 g  = su * inv;                                                 \
    const f32x2 m0v = nb0 + z0 * g, m1v = nb1 + z1 * g, m2v = nb2 + z2 * g,    \
                m3v = nb3 + z3 * g, m4v = nb4 + z4 * g;                        \
    *(f32x2*)p0 = m0v; *(f32x2*)p1 = m1v; *(f32x2*)p2 = m2v;                   \
    *(f32x2*)p3 = m3v; *(f32x2*)p4 = m4v;                                      \
    baseW = (base + 1) & 255;                                                  \
    ptrW  = ptr + 1.0f; if (ptrW >= 256.0f) ptrW -= 256.0f;                    \
    wnb0 = m1v; wnb1 = m2v; wnb2 = m3v; wnb3 = m4v;                            \
    wp0 = p1; wp1 = p2; wp2 = p3; wp3 = p4;                                    \
    wp4 = mem + (((base + 3) & 255) << 7) + 2 * l;                             \
    wnb4 = *(f32x2*)wp4;                                                       \
    jtW_pre = jd[baseW];                                                       \
    jt_cur  = jt_nxt;                                                          \
    /* precompute next step's walk ctx (operands+association identical to     \
       what the walk branch would compute) */                                  \
    ctxWp = inv * (((wnb0 * z0 + wnb1 * z1) + (wnb2 * z2 + wnb3 * z3))         \
                   + wnb4 * z4);                                               \
    /* LN + gate */                                                            \
    const float mu   = s1 * (1.0f / En);                                       \
    const float var  = s2 * (1.0f / En) - mu * mu;                             \
    const float rstd = __builtin_amdgcn_rsqf(var + LN_EPS);                    \
    hid = (su - mu) * rstd * lnw + lnb;                                        \
    jl  = s3 + bgs;                                                            \
}

    for (int k = 0; k < 64; ++k) {
        #pragma unroll
        for (int g = 0; g < 4; ++g) {
            const int tb  = k * 4 + g;
            int tbn = tb + 1; if (tbn > 255) tbn = 255;
            // prefetch next group: buf[(tbn>>2)%3] is never producer-active
            const float* sb = stg + ((tbn >> 2) % 3) * 2048 + (tbn & 3) * 512 + 4 * l;
            float4 B0 = *(const float4*)sb;
            float4 B1 = *(const float4*)(sb + 256);
            SSTEP(A0.x, A1.x)
            SSTEP(A0.y, A1.y)
            SSTEP(A0.z, A1.z)
            SSTEP(A0.w, A1.w)
            A0 = B0; A1 = B1;
        }
        __syncthreads();               // chunk boundary (chunk k+2 staged)
    }
#undef SSTEP

    // epilogue: logits = hid @ Wo^T + bo
    __builtin_amdgcn_s_setprio(0);
    mem[l] = hid[0]; mem[64 + l] = hid[1];
    __syncthreads();                   // final
    const float4* w4 = (const float4*)(Wo + l * En);
    const float4* h4 = (const float4*)mem;
    float a0 = 0.f, a1 = 0.f, a2 = 0.f, a3 = 0.f;
    #pragma unroll
    for (int i = 0; i < En / 4; ++i) {
        float4 wv = w4[i]; float4 hv = h4[i];
        a0 += wv.x * hv.x; a1 += wv.y * hv.y; a2 += wv.z * hv.z; a3 += wv.w * hv.w;
    }
    out[b * NOUTn + l] = (a0 + a1) + (a2 + a3) + bo[l];
}

extern "C" void kernel_launch(void* const* d_in, const int* in_sizes, int n_in,
                              void* d_out, int out_size, void* d_ws, size_t ws_size,
                              hipStream_t stream) {
    const float* x            = (const float*)d_in[0];
    const float* pointer_init = (const float*)d_in[1];
    const float* W_in         = (const float*)d_in[2];
    const float* b_in         = (const float*)d_in[3];
    const float* ln_w         = (const float*)d_in[4];
    const float* ln_b         = (const float*)d_in[5];
    const float* jump_dest    = (const float*)d_in[6];
    const float* Wg           = (const float*)d_in[7];
    const float* bg           = (const float*)d_in[8];
    const float* cs           = (const float*)d_in[9];
    const float* Wo           = (const float*)d_in[10];
    const float* bo           = (const float*)d_in[11];
    float* out = (float*)d_out;
    (void)d_ws; (void)ws_size;   // zero workspace: ws bytes are re-poisoned
                                 // per rep and billed (~270us for 128MB, R10)

    (void)hipFuncSetAttribute((const void*)fused2_kernel,
                              hipFuncAttributeMaxDynamicSharedMemorySize, LDSF_BYTES);
    fused2_kernel<<<Bn, 192, LDSF_BYTES, stream>>>(
        x, pointer_init, W_in, b_in, ln_w, ln_b, jump_dest, Wg, bg, cs,
        Wo, bo, out);
}